// Round 1
// 2719.534 us; speedup vs baseline: 1.6332x; 1.6332x over previous
//
#include <hip/hip_runtime.h>
#include <hip/hip_bf16.h>
#include <cstdint>
#include <cstddef>

#define HIDDEN 4096
#define INTER  16384
#define NTOK   8192   // 4*2048 tokens
#define LN_EPS 1e-5f

typedef unsigned short u16;
typedef u16   u16x8 __attribute__((ext_vector_type(8)));
typedef __bf16 bf16x8 __attribute__((ext_vector_type(8)));
typedef float  f32x4 __attribute__((ext_vector_type(4)));

__device__ __forceinline__ u16 f2bf(float f) {
    union { float f; unsigned int ui; } x;
    x.f = f;
    unsigned int u = x.ui;
    return (u16)((u + 0x7FFFu + ((u >> 16) & 1u)) >> 16);  // round-nearest-even
}

__device__ __forceinline__ void gl_lds16(const u16* g, u16* l) {
    __builtin_amdgcn_global_load_lds(
        (const __attribute__((address_space(1))) void*)g,
        (__attribute__((address_space(3))) void*)l,
        16, 0, 0);
}

// ---------------------------------------------------------------------------
// Cast fp32 [K,N] -> bf16 [N,K] (transpose). Tile 64x64 via LDS.
// ---------------------------------------------------------------------------
#define TDIM 64
__global__ __launch_bounds__(256) void cvt_transpose(const float* __restrict__ in,
                                                     u16* __restrict__ out,
                                                     int K, int N) {
    __shared__ float tile[TDIM][TDIM + 1];
    const int bn = blockIdx.x * TDIM;
    const int bk = blockIdx.y * TDIM;
    const int t  = threadIdx.x;
#pragma unroll
    for (int it = 0; it < 4; ++it) {
        int idx = it * 256 + t;
        int r = idx >> 4;
        int c = (idx & 15) * 4;
        const float4 v = *(const float4*)(in + (size_t)(bk + r) * N + bn + c);
        tile[r][c]     = v.x;
        tile[r][c + 1] = v.y;
        tile[r][c + 2] = v.z;
        tile[r][c + 3] = v.w;
    }
    __syncthreads();
#pragma unroll
    for (int it = 0; it < 2; ++it) {
        int idx = it * 256 + t;
        int r = idx >> 3;
        int c = (idx & 7) * 8;
        u16x8 o;
#pragma unroll
        for (int j = 0; j < 8; ++j) o[j] = f2bf(tile[c + j][r]);
        *(u16x8*)(out + (size_t)(bn + r) * K + bk + c) = o;
    }
}

// ---------------------------------------------------------------------------
// res = input + residual + bias; ln = bf16(LN(res)*gamma + beta).
// ---------------------------------------------------------------------------
__global__ __launch_bounds__(256) void fused_add_ln(const float* __restrict__ in,
                                                    const float* __restrict__ resid,
                                                    const float* __restrict__ bias,
                                                    const float* __restrict__ gamma,
                                                    const float* __restrict__ beta,
                                                    u16* __restrict__ out) {
    const int row = blockIdx.x;
    const size_t base = (size_t)row * HIDDEN;
    const int t = threadIdx.x;
    const int c0 = t * 16;
    float v[16];
    float s = 0.f, s2 = 0.f;
#pragma unroll
    for (int g = 0; g < 4; ++g) {
        float4 vi = *(const float4*)(in    + base + c0 + g * 4);
        float4 vr = *(const float4*)(resid + base + c0 + g * 4);
        float4 vb = *(const float4*)(bias  + c0 + g * 4);
        float xs[4] = {vi.x + vr.x + vb.x, vi.y + vr.y + vb.y,
                       vi.z + vr.z + vb.z, vi.w + vr.w + vb.w};
#pragma unroll
        for (int j = 0; j < 4; ++j) {
            float x = xs[j];
            v[g * 4 + j] = x;
            s += x;
            s2 += x * x;
        }
    }
#pragma unroll
    for (int off = 32; off > 0; off >>= 1) {
        s  += __shfl_down(s, off, 64);
        s2 += __shfl_down(s2, off, 64);
    }
    __shared__ float sred[4], s2red[4], stats[2];
    const int wave = t >> 6, lane = t & 63;
    if (lane == 0) { sred[wave] = s; s2red[wave] = s2; }
    __syncthreads();
    if (t == 0) {
        float ts  = sred[0] + sred[1] + sred[2] + sred[3];
        float ts2 = s2red[0] + s2red[1] + s2red[2] + s2red[3];
        float mean = ts * (1.0f / HIDDEN);
        float var  = ts2 * (1.0f / HIDDEN) - mean * mean;
        stats[0] = mean;
        stats[1] = rsqrtf(var + LN_EPS);
    }
    __syncthreads();
    const float mean = stats[0], rstd = stats[1];
#pragma unroll
    for (int g = 0; g < 2; ++g) {
        u16x8 o;
#pragma unroll
        for (int j = 0; j < 8; ++j) {
            int e = g * 8 + j;
            float gm = gamma[c0 + e];
            float bt = beta[c0 + e];
            o[j] = f2bf((v[e] - mean) * rstd * gm + bt);
        }
        *(u16x8*)(out + base + c0 + g * 8) = o;
    }
}

// ---------------------------------------------------------------------------
// 256x256 8-phase GEMM (m201 template, plain HIP):
//   C[M,N] = A[M,K] * BT[N,K]^T, bf16 in, fp32 accum.
//   BK=64, 8 waves (2M x 4N), per-wave 128x64 output, 16x16x32 MFMA.
//   LDS 128KB: double-buffered A(256x64) + B(256x64), XOR slot-swizzle
//   (slot ^= row&7, same involution on pre-swizzled global src + ds_read).
//   Counted vmcnt(4) once per K-tile (2 half-tiles stay in flight).
// EPI==0: Cb = bf16(gelu_tanh(acc + b0f[col]))
// EPI==1: Cf = acc + in_f + res_f + b0f[col] + b1f[col]
// ---------------------------------------------------------------------------
template <int IH>
__device__ __forceinline__ void lda_t(bf16x8 (&af)[4][2], const u16* p0, int s0, int s1) {
#pragma unroll
    for (int ii = 0; ii < 4; ++ii) {
        const u16* p = p0 + (IH * 64 + ii * 16) * 64;
        af[ii][0] = *(const bf16x8*)(p + s0);
        af[ii][1] = *(const bf16x8*)(p + s1);
    }
}

template <int JH>
__device__ __forceinline__ void ldb_t(bf16x8 (&bf)[4][2], const u16* p0, int s0, int s1) {
#pragma unroll
    for (int jj = 0; jj < 2; ++jj) {
        const u16* p = p0 + (JH * 2 + jj) * 1024;
        bf[JH * 2 + jj][0] = *(const bf16x8*)(p + s0);
        bf[JH * 2 + jj][1] = *(const bf16x8*)(p + s1);
    }
}

template <int IH, int JH>
__device__ __forceinline__ void mfma_q(f32x4 (&acc)[8][4], const bf16x8 (&af)[4][2],
                                       const bf16x8 (&bf)[4][2]) {
#pragma unroll
    for (int ii = 0; ii < 4; ++ii)
#pragma unroll
        for (int jj = 0; jj < 2; ++jj)
#pragma unroll
            for (int kk = 0; kk < 2; ++kk)
                acc[IH * 4 + ii][JH * 2 + jj] = __builtin_amdgcn_mfma_f32_16x16x32_bf16(
                    af[ii][kk], bf[JH * 2 + jj][kk], acc[IH * 4 + ii][JH * 2 + jj], 0, 0, 0);
}

template <int EPI>
__global__ __launch_bounds__(512, 2) void gemm256(const u16* __restrict__ A,
                                                  const u16* __restrict__ BT,
                                                  u16* __restrict__ Cb,
                                                  float* __restrict__ Cf,
                                                  const float* __restrict__ b0f,
                                                  const float* __restrict__ b1f,
                                                  const float* __restrict__ in_f,
                                                  const float* __restrict__ res_f,
                                                  int M, int N, int K) {
    (void)M;
    extern __shared__ u16 lds[];          // [A buf0|A buf1|B buf0|B buf1] 4x32KB
    const int t    = threadIdx.x;
    const int wave = t >> 6;
    const int lane = t & 63;
    const int l16  = lane & 15;
    const int quad = lane >> 4;
    const int xlow = l16 & 7;
    const int rl   = lane >> 3;                   // 0..7
    const int scol = ((lane & 7) ^ rl) * 8;       // pre-swizzled global src col (elems)

    // XCD-aware bijective swizzle (nwg % 8 == 0 for both launches)
    const int gx   = gridDim.x;
    const int nwg  = gx * gridDim.y;
    const int orig = blockIdx.y * gx + blockIdx.x;
    const int wg   = (orig & 7) * (nwg >> 3) + (orig >> 3);
    const int m0   = (wg / gx) * 256;
    const int n0   = (wg % gx) * 256;

    const int wm = (wave >> 2) * 128;
    const int wn = (wave & 3) * 64;

    u16* const as0 = lds;                 // A tiles: buf*16384
    u16* const bs0 = lds + 32768;         // B tiles: buf*16384

    const u16* pA = A  + (size_t)(m0 + wave * 16 + rl) * K + scol;
    const u16* pB = BT + (size_t)(n0 + wave * 16 + rl) * K + scol;

    const int aoff = (wm + l16) * 64;
    const int boff = (wn + l16) * 64;
    const int s0   = (quad ^ xlow) * 8;   // swizzled slot, kk=0 (elems)
    const int s1   = s0 ^ 32;             // kk=1: slot^4 -> +-32 elems

    auto stage = [&](const u16* pbase, int hh, int kcol, u16* ldst) {
#pragma unroll
        for (int call = 0; call < 2; ++call)
            gl_lds16(pbase + (size_t)(hh * 128 + call * 8) * (size_t)K + kcol,
                     ldst + hh * 8192 + (wave * 2 + call) * 512);
    };

    f32x4 acc[8][4];
#pragma unroll
    for (int i = 0; i < 8; ++i)
#pragma unroll
        for (int j = 0; j < 4; ++j)
            acc[i][j] = f32x4{0.f, 0.f, 0.f, 0.f};

    const int NT = K >> 6;

    // ---- prologue: stage t0.{A0,A1,B0,B1}, then t1.{B0,B1} (newest)
    stage(pA, 0, 0, as0);
    stage(pA, 1, 0, as0);
    stage(pB, 0, 0, bs0);
    stage(pB, 1, 0, bs0);
    if (NT > 1) {
        stage(pB, 0, 64, bs0 + 16384);
        stage(pB, 1, 64, bs0 + 16384);
        asm volatile("s_waitcnt vmcnt(4)" ::: "memory");
    } else {
        asm volatile("s_waitcnt vmcnt(0)" ::: "memory");
    }
    __builtin_amdgcn_s_barrier();

    bf16x8 af[4][2], bfv[4][2];

    for (int kt = 0; kt < NT; ++kt) {
        const int buf  = kt & 1;
        const u16* as_ = as0 + buf * 16384;
        const u16* bs_ = bs0 + buf * 16384;
        u16* an = as0 + (buf ^ 1) * 16384;   // A(kt+1) dest (idle buffer)
        u16* bw = bs0 + buf * 16384;         // B(kt+2) dest (B region dead after P1)
        const int  kcA = (kt + 1) << 6;
        const int  kcB = (kt + 2) << 6;
        const bool stA = (kt + 1 < NT);
        const bool stB = (kt + 2 < NT);

        // ---- P0: read A-half0 + B j0-1; stage A(kt+1) half0
        lda_t<0>(af, as_ + aoff, s0, s1);
        ldb_t<0>(bfv, bs_ + boff, s0, s1);
        if (stA) stage(pA, 0, kcA, an);
        __builtin_amdgcn_s_barrier();
        asm volatile("s_waitcnt lgkmcnt(0)" ::: "memory");
        __builtin_amdgcn_s_setprio(1);
        mfma_q<0, 0>(acc, af, bfv);
        __builtin_amdgcn_s_setprio(0);
        __builtin_amdgcn_s_barrier();

        // ---- P1: read B j2-3; stage A(kt+1) half1
        ldb_t<1>(bfv, bs_ + boff, s0, s1);
        if (stA) stage(pA, 1, kcA, an);
        __builtin_amdgcn_s_barrier();
        asm volatile("s_waitcnt lgkmcnt(0)" ::: "memory");
        __builtin_amdgcn_s_setprio(1);
        mfma_q<0, 1>(acc, af, bfv);
        __builtin_amdgcn_s_setprio(0);
        __builtin_amdgcn_s_barrier();

        // ---- P2: read A-half1; stage B(kt+2) half0 (into current buf: B dead)
        lda_t<1>(af, as_ + aoff, s0, s1);
        if (stB) stage(pB, 0, kcB, bw);
        __builtin_amdgcn_s_barrier();
        asm volatile("s_waitcnt lgkmcnt(0)" ::: "memory");
        __builtin_amdgcn_s_setprio(1);
        mfma_q<1, 1>(acc, af, bfv);
        __builtin_amdgcn_s_setprio(0);
        __builtin_amdgcn_s_barrier();

        // ---- P3: stage B(kt+2) half1; counted vmcnt before tile boundary
        if (stB) stage(pB, 1, kcB, bw);
        __builtin_amdgcn_s_barrier();
        __builtin_amdgcn_s_setprio(1);
        mfma_q<1, 0>(acc, af, bfv);
        __builtin_amdgcn_s_setprio(0);
        if (stB) asm volatile("s_waitcnt vmcnt(4)" ::: "memory");
        else     asm volatile("s_waitcnt vmcnt(0)" ::: "memory");
        __builtin_amdgcn_s_barrier();
    }

    // ---- epilogue. C/D layout: col = lane&15, row = quad*4 + r.
#pragma unroll
    for (int i = 0; i < 8; ++i) {
#pragma unroll
        for (int j = 0; j < 4; ++j) {
            const int col = n0 + wn + j * 16 + l16;
            float badd;
            if (EPI == 0) badd = b0f[col];
            else          badd = b0f[col] + b1f[col];
#pragma unroll
            for (int r = 0; r < 4; ++r) {
                const int rowi = m0 + wm + i * 16 + quad * 4 + r;
                float x = acc[i][j][r];
                if (EPI == 0) {
                    x += badd;
                    float u  = 0.7978845608f * (x + 0.044715f * x * x * x);
                    float sg = 1.0f / (1.0f + __expf(-2.0f * u));
                    Cb[(size_t)rowi * N + col] = f2bf(x * sg);
                } else {
                    const size_t off = (size_t)rowi * N + col;
                    Cf[off] = x + in_f[off] + res_f[off] + badd;
                }
            }
        }
    }
}

// ---------------------------------------------------------------------------
extern "C" void kernel_launch(void* const* d_in, const int* in_sizes, int n_in,
                              void* d_out, int out_size, void* d_ws, size_t ws_size,
                              hipStream_t stream) {
    const float* input    = (const float*)d_in[0];
    const float* residual = (const float*)d_in[1];
    // d_in[2] residual_norm: unused by the reference path
    const float* bias     = (const float*)d_in[3];
    const float* attn_nw  = (const float*)d_in[4];
    const float* attn_nb  = (const float*)d_in[5];
    const float* inter_w  = (const float*)d_in[6];   // [HIDDEN, INTER] fp32
    const float* inter_b  = (const float*)d_in[7];
    const float* output_w = (const float*)d_in[8];   // [INTER, HIDDEN] fp32
    const float* output_b = (const float*)d_in[9];
    float* out = (float*)d_out;

    char* ws = (char*)d_ws;
    u16* w1t   = (u16*)(ws);                    // bf16 [INTER, HIDDEN]  128MB
    u16* w2t   = (u16*)(ws + 134217728);        // bf16 [HIDDEN, INTER]  128MB
    u16* ln    = (u16*)(ws + 268435456);        // bf16 [NTOK, HIDDEN]    64MB
    u16* inter = (u16*)(ws + 335544320);        // bf16 [NTOK, INTER]    256MB

    static int once = [] {
        hipFuncSetAttribute(reinterpret_cast<const void*>(gemm256<0>),
                            hipFuncAttributeMaxDynamicSharedMemorySize, 131072);
        hipFuncSetAttribute(reinterpret_cast<const void*>(gemm256<1>),
                            hipFuncAttributeMaxDynamicSharedMemorySize, 131072);
        return 0;
    }();
    (void)once;

    cvt_transpose<<<dim3(INTER / TDIM, HIDDEN / TDIM), 256, 0, stream>>>(inter_w, w1t, HIDDEN, INTER);
    cvt_transpose<<<dim3(HIDDEN / TDIM, INTER / TDIM), 256, 0, stream>>>(output_w, w2t, INTER, HIDDEN);
    fused_add_ln<<<NTOK, 256, 0, stream>>>(input, residual, bias, attn_nw, attn_nb, ln);
    gemm256<0><<<dim3(INTER / 256, NTOK / 256), 512, 131072, stream>>>(
        ln, w1t, inter, nullptr, inter_b, nullptr, nullptr, nullptr, NTOK, INTER, HIDDEN);
    gemm256<1><<<dim3(HIDDEN / 256, NTOK / 256), 512, 131072, stream>>>(
        inter, w2t, nullptr, out, bias, output_b, input, residual, NTOK, HIDDEN, INTER);
}

// Round 2
// 2684.217 us; speedup vs baseline: 1.6547x; 1.0132x over previous
//
#include <hip/hip_runtime.h>
#include <hip/hip_bf16.h>
#include <cstdint>
#include <cstddef>

#define HIDDEN 4096
#define INTER  16384
#define NTOK   8192   // 4*2048 tokens
#define LN_EPS 1e-5f

typedef unsigned short u16;
typedef u16   u16x8 __attribute__((ext_vector_type(8)));
typedef __bf16 bf16x8 __attribute__((ext_vector_type(8)));
typedef float  f32x4 __attribute__((ext_vector_type(4)));

__device__ __forceinline__ u16 f2bf(float f) {
    union { float f; unsigned int ui; } x;
    x.f = f;
    unsigned int u = x.ui;
    return (u16)((u + 0x7FFFu + ((u >> 16) & 1u)) >> 16);  // round-nearest-even
}

__device__ __forceinline__ void gl_lds16(const u16* g, u16* l) {
    __builtin_amdgcn_global_load_lds(
        (const __attribute__((address_space(1))) void*)g,
        (__attribute__((address_space(3))) void*)l,
        16, 0, 0);
}

// ---------------------------------------------------------------------------
// Cast fp32 [K,N] -> bf16 [N,K] (transpose). Tile 64x64 via LDS.
// ---------------------------------------------------------------------------
#define TDIM 64
__global__ __launch_bounds__(256) void cvt_transpose(const float* __restrict__ in,
                                                     u16* __restrict__ out,
                                                     int K, int N) {
    __shared__ float tile[TDIM][TDIM + 1];
    const int bn = blockIdx.x * TDIM;
    const int bk = blockIdx.y * TDIM;
    const int t  = threadIdx.x;
#pragma unroll
    for (int it = 0; it < 4; ++it) {
        int idx = it * 256 + t;
        int r = idx >> 4;
        int c = (idx & 15) * 4;
        const float4 v = *(const float4*)(in + (size_t)(bk + r) * N + bn + c);
        tile[r][c]     = v.x;
        tile[r][c + 1] = v.y;
        tile[r][c + 2] = v.z;
        tile[r][c + 3] = v.w;
    }
    __syncthreads();
#pragma unroll
    for (int it = 0; it < 2; ++it) {
        int idx = it * 256 + t;
        int r = idx >> 3;
        int c = (idx & 7) * 8;
        u16x8 o;
#pragma unroll
        for (int j = 0; j < 8; ++j) o[j] = f2bf(tile[c + j][r]);
        *(u16x8*)(out + (size_t)(bn + r) * K + bk + c) = o;
    }
}

// ---------------------------------------------------------------------------
// res = input + residual + bias; ln = bf16(LN(res)*gamma + beta).
// ---------------------------------------------------------------------------
__global__ __launch_bounds__(256) void fused_add_ln(const float* __restrict__ in,
                                                    const float* __restrict__ resid,
                                                    const float* __restrict__ bias,
                                                    const float* __restrict__ gamma,
                                                    const float* __restrict__ beta,
                                                    u16* __restrict__ out) {
    const int row = blockIdx.x;
    const size_t base = (size_t)row * HIDDEN;
    const int t = threadIdx.x;
    const int c0 = t * 16;
    float v[16];
    float s = 0.f, s2 = 0.f;
#pragma unroll
    for (int g = 0; g < 4; ++g) {
        float4 vi = *(const float4*)(in    + base + c0 + g * 4);
        float4 vr = *(const float4*)(resid + base + c0 + g * 4);
        float4 vb = *(const float4*)(bias  + c0 + g * 4);
        float xs[4] = {vi.x + vr.x + vb.x, vi.y + vr.y + vb.y,
                       vi.z + vr.z + vb.z, vi.w + vr.w + vb.w};
#pragma unroll
        for (int j = 0; j < 4; ++j) {
            float x = xs[j];
            v[g * 4 + j] = x;
            s += x;
            s2 += x * x;
        }
    }
#pragma unroll
    for (int off = 32; off > 0; off >>= 1) {
        s  += __shfl_down(s, off, 64);
        s2 += __shfl_down(s2, off, 64);
    }
    __shared__ float sred[4], s2red[4], stats[2];
    const int wave = t >> 6, lane = t & 63;
    if (lane == 0) { sred[wave] = s; s2red[wave] = s2; }
    __syncthreads();
    if (t == 0) {
        float ts  = sred[0] + sred[1] + sred[2] + sred[3];
        float ts2 = s2red[0] + s2red[1] + s2red[2] + s2red[3];
        float mean = ts * (1.0f / HIDDEN);
        float var  = ts2 * (1.0f / HIDDEN) - mean * mean;
        stats[0] = mean;
        stats[1] = rsqrtf(var + LN_EPS);
    }
    __syncthreads();
    const float mean = stats[0], rstd = stats[1];
#pragma unroll
    for (int g = 0; g < 2; ++g) {
        u16x8 o;
#pragma unroll
        for (int j = 0; j < 8; ++j) {
            int e = g * 8 + j;
            float gm = gamma[c0 + e];
            float bt = beta[c0 + e];
            o[j] = f2bf((v[e] - mean) * rstd * gm + bt);
        }
        *(u16x8*)(out + base + c0 + g * 8) = o;
    }
}

// ---------------------------------------------------------------------------
// 256x256 8-phase GEMM (m201 template, plain HIP):
//   C[M,N] = A[M,K] * BT[N,K]^T, bf16 in, fp32 accum.
//   BK=64, 8 waves (2M x 4N), per-wave 128x64 output, 16x16x32 MFMA.
//   LDS 128KB: double-buffered A(256x64) + B(256x64), XOR slot-swizzle
//   (slot ^= row&7, same involution on pre-swizzled global src + ds_read).
//   Staging depth = 3 half-tiles in flight, boundary vmcnt(6) (m201 steady
//   state): B(T)h0@P2, B(T)h1+A(T)h0@P3 of tile T-2, A(T)h1@P0 of tile T-1.
// EPI==0: Cb = bf16(gelu_tanh(acc + b0f[col]))   + B-grouped XCD chunk order
// EPI==1: Cf = acc + in_f + res_f + b0f[col] + b1f[col]   (row-major order)
// ---------------------------------------------------------------------------
template <int IH>
__device__ __forceinline__ void lda_t(bf16x8 (&af)[4][2], const u16* p0, int s0, int s1) {
#pragma unroll
    for (int ii = 0; ii < 4; ++ii) {
        const u16* p = p0 + (IH * 64 + ii * 16) * 64;
        af[ii][0] = *(const bf16x8*)(p + s0);
        af[ii][1] = *(const bf16x8*)(p + s1);
    }
}

template <int JH>
__device__ __forceinline__ void ldb_t(bf16x8 (&bf)[4][2], const u16* p0, int s0, int s1) {
#pragma unroll
    for (int jj = 0; jj < 2; ++jj) {
        const u16* p = p0 + (JH * 2 + jj) * 1024;
        bf[JH * 2 + jj][0] = *(const bf16x8*)(p + s0);
        bf[JH * 2 + jj][1] = *(const bf16x8*)(p + s1);
    }
}

template <int IH, int JH>
__device__ __forceinline__ void mfma_q(f32x4 (&acc)[8][4], const bf16x8 (&af)[4][2],
                                       const bf16x8 (&bf)[4][2]) {
#pragma unroll
    for (int ii = 0; ii < 4; ++ii)
#pragma unroll
        for (int jj = 0; jj < 2; ++jj)
#pragma unroll
            for (int kk = 0; kk < 2; ++kk)
                acc[IH * 4 + ii][JH * 2 + jj] = __builtin_amdgcn_mfma_f32_16x16x32_bf16(
                    af[ii][kk], bf[JH * 2 + jj][kk], acc[IH * 4 + ii][JH * 2 + jj], 0, 0, 0);
}

template <int EPI>
__global__ __launch_bounds__(512, 2) void gemm256(const u16* __restrict__ A,
                                                  const u16* __restrict__ BT,
                                                  u16* __restrict__ Cb,
                                                  float* __restrict__ Cf,
                                                  const float* __restrict__ b0f,
                                                  const float* __restrict__ b1f,
                                                  const float* __restrict__ in_f,
                                                  const float* __restrict__ res_f,
                                                  int M, int N, int K) {
    (void)M;
    extern __shared__ u16 lds[];          // [A buf0|A buf1|B buf0|B buf1] 4x32KB
    const int t    = threadIdx.x;
    const int wave = t >> 6;
    const int lane = t & 63;
    const int l16  = lane & 15;
    const int quad = lane >> 4;
    const int xlow = l16 & 7;
    const int rl   = lane >> 3;                   // 0..7
    const int scol = ((lane & 7) ^ rl) * 8;       // pre-swizzled global src col (elems)

    // XCD-aware bijective swizzle. Within-XCD chunk order:
    //  EPI==0: B-panel-grouped (consecutive blocks share n0, step m0) — B is
    //          the 128MB operand; fetch it once per XCD, keep 4 A panels hot.
    //  EPI==1: row-major (A is the 256MB operand, already reused consecutively).
    const int gx   = gridDim.x;
    const int nwg  = gx * gridDim.y;
    const int cpx  = nwg >> 3;
    const int orig = blockIdx.y * gx + blockIdx.x;
    const int xcd  = orig & 7;
    const int c    = orig >> 3;           // index within XCD chunk
    int mi, ni;
    const int mpc  = cpx / gx;            // m-rows per chunk (4 for both launches)
    if (EPI == 0 && mpc * gx == cpx) {
        mi = xcd * mpc + (c % mpc);
        ni = c / mpc;
    } else {
        const int wg = xcd * cpx + c;
        mi = wg / gx;
        ni = wg % gx;
    }
    const int m0 = mi * 256;
    const int n0 = ni * 256;

    const int wm = (wave >> 2) * 128;
    const int wn = (wave & 3) * 64;

    u16* const as0 = lds;                 // A tiles: buf*16384
    u16* const bs0 = lds + 32768;         // B tiles: buf*16384

    const u16* pA = A  + (size_t)(m0 + wave * 16 + rl) * K + scol;
    const u16* pB = BT + (size_t)(n0 + wave * 16 + rl) * K + scol;

    const int aoff = (wm + l16) * 64;
    const int boff = (wn + l16) * 64;
    const int s0   = (quad ^ xlow) * 8;   // swizzled slot, kk=0 (elems)
    const int s1   = s0 ^ 32;             // kk=1: slot^4 -> +-32 elems

    auto stage = [&](const u16* pbase, int hh, int kcol, u16* ldst) {
#pragma unroll
        for (int call = 0; call < 2; ++call)
            gl_lds16(pbase + (size_t)(hh * 128 + call * 8) * (size_t)K + kcol,
                     ldst + hh * 8192 + (wave * 2 + call) * 512);
    };

    f32x4 acc[8][4];
#pragma unroll
    for (int i = 0; i < 8; ++i)
#pragma unroll
        for (int j = 0; j < 4; ++j)
            acc[i][j] = f32x4{0.f, 0.f, 0.f, 0.f};

    const int NT = K >> 6;

    // ---- prologue: tile0 fully; tile1: B h0,h1 + A h0 (A h1 goes at P0 of kt=0)
    stage(pA, 0, 0, as0);
    stage(pA, 1, 0, as0);
    stage(pB, 0, 0, bs0);
    stage(pB, 1, 0, bs0);
    if (NT > 1) {
        stage(pB, 0, 64, bs0 + 16384);
        stage(pB, 1, 64, bs0 + 16384);
        stage(pA, 0, 64, as0 + 16384);
        asm volatile("s_waitcnt vmcnt(6)" ::: "memory");
    } else {
        asm volatile("s_waitcnt vmcnt(0)" ::: "memory");
    }
    __builtin_amdgcn_s_barrier();

    bf16x8 af[4][2], bfv[4][2];

    for (int kt = 0; kt < NT; ++kt) {
        const int buf  = kt & 1;
        const u16* as_ = as0 + buf * 16384;
        const u16* bs_ = bs0 + buf * 16384;
        u16* an1 = as0 + (buf ^ 1) * 16384;  // A(kt+1): h1 staged @P0
        u16* a2  = as0 + buf * 16384;        // A(kt+2): h0 staged @P3 (A dead after P2)
        u16* b2  = bs0 + buf * 16384;        // B(kt+2): h0@P2, h1@P3 (B dead after P1)
        const int  kc1 = (kt + 1) << 6;
        const int  kc2 = (kt + 2) << 6;
        const bool st1 = (kt + 1 < NT);
        const bool st2 = (kt + 2 < NT);

        // ---- P0: read A(kt)h0 + B(kt)j01; stage A(kt+1)h1
        lda_t<0>(af, as_ + aoff, s0, s1);
        ldb_t<0>(bfv, bs_ + boff, s0, s1);
        if (st1) stage(pA, 1, kc1, an1);
        __builtin_amdgcn_s_barrier();
        asm volatile("s_waitcnt lgkmcnt(0)" ::: "memory");
        __builtin_amdgcn_s_setprio(1);
        mfma_q<0, 0>(acc, af, bfv);
        __builtin_amdgcn_s_setprio(0);
        __builtin_amdgcn_s_barrier();

        // ---- P1: read B(kt)j23
        ldb_t<1>(bfv, bs_ + boff, s0, s1);
        __builtin_amdgcn_s_barrier();
        asm volatile("s_waitcnt lgkmcnt(0)" ::: "memory");
        __builtin_amdgcn_s_setprio(1);
        mfma_q<0, 1>(acc, af, bfv);
        __builtin_amdgcn_s_setprio(0);
        __builtin_amdgcn_s_barrier();

        // ---- P2: read A(kt)h1; stage B(kt+2)h0
        lda_t<1>(af, as_ + aoff, s0, s1);
        if (st2) stage(pB, 0, kc2, b2);
        __builtin_amdgcn_s_barrier();
        asm volatile("s_waitcnt lgkmcnt(0)" ::: "memory");
        __builtin_amdgcn_s_setprio(1);
        mfma_q<1, 1>(acc, af, bfv);
        __builtin_amdgcn_s_setprio(0);
        __builtin_amdgcn_s_barrier();

        // ---- P3: stage B(kt+2)h1 + A(kt+2)h0; boundary vmcnt(6)
        if (st2) {
            stage(pB, 1, kc2, b2);
            stage(pA, 0, kc2, a2);
        }
        __builtin_amdgcn_s_barrier();
        __builtin_amdgcn_s_setprio(1);
        mfma_q<1, 0>(acc, af, bfv);
        __builtin_amdgcn_s_setprio(0);
        if (st2)      asm volatile("s_waitcnt vmcnt(6)" ::: "memory");
        else if (st1) asm volatile("s_waitcnt vmcnt(0)" ::: "memory");
        __builtin_amdgcn_s_barrier();
    }

    // ---- epilogue. C/D layout: col = lane&15, row = quad*4 + r.
#pragma unroll
    for (int i = 0; i < 8; ++i) {
#pragma unroll
        for (int j = 0; j < 4; ++j) {
            const int col = n0 + wn + j * 16 + l16;
            float badd;
            if (EPI == 0) badd = b0f[col];
            else          badd = b0f[col] + b1f[col];
#pragma unroll
            for (int r = 0; r < 4; ++r) {
                const int rowi = m0 + wm + i * 16 + quad * 4 + r;
                float x = acc[i][j][r];
                if (EPI == 0) {
                    x += badd;
                    float u  = 0.7978845608f * (x + 0.044715f * x * x * x);
                    float sg = 1.0f / (1.0f + __expf(-2.0f * u));
                    Cb[(size_t)rowi * N + col] = f2bf(x * sg);
                } else {
                    const size_t off = (size_t)rowi * N + col;
                    Cf[off] = x + in_f[off] + res_f[off] + badd;
                }
            }
        }
    }
}

// ---------------------------------------------------------------------------
extern "C" void kernel_launch(void* const* d_in, const int* in_sizes, int n_in,
                              void* d_out, int out_size, void* d_ws, size_t ws_size,
                              hipStream_t stream) {
    const float* input    = (const float*)d_in[0];
    const float* residual = (const float*)d_in[1];
    // d_in[2] residual_norm: unused by the reference path
    const float* bias     = (const float*)d_in[3];
    const float* attn_nw  = (const float*)d_in[4];
    const float* attn_nb  = (const float*)d_in[5];
    const float* inter_w  = (const float*)d_in[6];   // [HIDDEN, INTER] fp32
    const float* inter_b  = (const float*)d_in[7];
    const float* output_w = (const float*)d_in[8];   // [INTER, HIDDEN] fp32
    const float* output_b = (const float*)d_in[9];
    float* out = (float*)d_out;

    char* ws = (char*)d_ws;
    u16* w1t   = (u16*)(ws);                    // bf16 [INTER, HIDDEN]  128MB
    u16* w2t   = (u16*)(ws + 134217728);        // bf16 [HIDDEN, INTER]  128MB
    u16* ln    = (u16*)(ws + 268435456);        // bf16 [NTOK, HIDDEN]    64MB
    u16* inter = (u16*)(ws + 335544320);        // bf16 [NTOK, INTER]    256MB

    static int once = [] {
        hipFuncSetAttribute(reinterpret_cast<const void*>(gemm256<0>),
                            hipFuncAttributeMaxDynamicSharedMemorySize, 131072);
        hipFuncSetAttribute(reinterpret_cast<const void*>(gemm256<1>),
                            hipFuncAttributeMaxDynamicSharedMemorySize, 131072);
        return 0;
    }();
    (void)once;

    cvt_transpose<<<dim3(INTER / TDIM, HIDDEN / TDIM), 256, 0, stream>>>(inter_w, w1t, HIDDEN, INTER);
    cvt_transpose<<<dim3(HIDDEN / TDIM, INTER / TDIM), 256, 0, stream>>>(output_w, w2t, INTER, HIDDEN);
    fused_add_ln<<<NTOK, 256, 0, stream>>>(input, residual, bias, attn_nw, attn_nb, ln);
    gemm256<0><<<dim3(INTER / 256, NTOK / 256), 512, 131072, stream>>>(
        ln, w1t, inter, nullptr, inter_b, nullptr, nullptr, nullptr, NTOK, INTER, HIDDEN);
    gemm256<1><<<dim3(HIDDEN / 256, NTOK / 256), 512, 131072, stream>>>(
        inter, w2t, nullptr, out, bias, output_b, input, residual, NTOK, HIDDEN, INTER);
}